// Round 1
// baseline (2363.943 us; speedup 1.0000x reference)
//
#include <hip/hip_runtime.h>
#include <math.h>

#define NROWS 8192
#define DIM   1024
#define KSEL  5
#define TOPK  6
#define QB    64
#define KB    64
#define DC    32
#define NSLICE 4
#define KPS   (NROWS / NSLICE)   // keys per slice = 2048
#define KT    (KPS / KB)         // key tiles per slice = 32
#define LST   68                 // LDS row stride (pad 4, keeps 16B alignment)

// ---------------------------------------------------------------------------
// ws layout:
//   [0]                : int match counter (memset 0 each launch)
//   [256]              : qinv  (NROWS floats)
//   [256+4*NROWS]      : kinv  (NROWS floats)
//   [256+8*NROWS]      : partials float2[NROWS][16][TOPK]  (~6 MB)
// ---------------------------------------------------------------------------

__device__ __forceinline__ bool better(float v, int id, float v2, int id2) {
    return (v > v2) || (v == v2 && id < id2);
}

__device__ __forceinline__ void insert6(float v, int id, float* tv, int* ti) {
    if (!better(v, id, tv[TOPK - 1], ti[TOPK - 1])) return;
    int j = TOPK - 1;
    while (j > 0 && better(v, id, tv[j - 1], ti[j - 1])) {
        tv[j] = tv[j - 1]; ti[j] = ti[j - 1]; --j;
    }
    tv[j] = v; ti[j] = id;
}

// --- 1) row inverse-norms ---------------------------------------------------
__global__ __launch_bounds__(256) void norm_kernel(
        const float* __restrict__ q, const float* __restrict__ kb,
        float* __restrict__ qinv, float* __restrict__ kinv) {
    int row = blockIdx.x;                       // 0 .. 2*NROWS-1
    int r   = (row < NROWS) ? row : row - NROWS;
    const float* src = (row < NROWS) ? q : kb;
    float4 v = *(const float4*)(src + (size_t)r * DIM + threadIdx.x * 4);
    float s = v.x * v.x + v.y * v.y + v.z * v.z + v.w * v.w;
    for (int o = 32; o; o >>= 1) s += __shfl_down(s, o, 64);
    __shared__ float wsum[4];
    int lane = threadIdx.x & 63, wid = threadIdx.x >> 6;
    if (lane == 0) wsum[wid] = s;
    __syncthreads();
    if (threadIdx.x == 0) {
        float t = wsum[0] + wsum[1] + wsum[2] + wsum[3];
        float inv = 1.0f / fmaxf(sqrtf(t), 1e-12f);
        ((row < NROWS) ? qinv : kinv)[r] = inv;
    }
}

// --- 2) fused fp32 GEMM + per-thread running top-6 --------------------------
__global__ __launch_bounds__(256) void simtopk_kernel(
        const float* __restrict__ Q, const float* __restrict__ Kb,
        const float* __restrict__ qinv, const float* __restrict__ kinv,
        float2* __restrict__ partials) {
    __shared__ float smem[2 * DC * LST];        // 4352 floats = 17408 B
    float (*As)[LST]   = (float (*)[LST])smem;                 // [DC][LST]
    float (*Bs)[LST]   = (float (*)[LST])(smem + DC * LST);    // [DC][LST]
    float (*Sims)[LST] = (float (*)[LST])smem;                 // [64][LST] (alias)

    const int tid   = threadIdx.x;
    const int qbase = blockIdx.x * QB;
    const int kbase = blockIdx.y * KPS;

    const int rg = tid >> 4;        // 0..15  (compute row group)
    const int cg = tid & 15;        // 0..15  (compute col group)

    const int sr = tid >> 3;        // 0..31  (staging row)
    const int sd = (tid & 7) * 4;   // 0..28  (staging d offset)

    const float invq0 = qinv[qbase + sr];
    const float invq1 = qinv[qbase + sr + 32];

    // per-thread top-6 over its (row = tid>>2, col subset = tid&3) stream
    float tv[TOPK]; int ti[TOPK];
#pragma unroll
    for (int i = 0; i < TOPK; ++i) { tv[i] = -INFINITY; ti[i] = 0x7fffffff; }
    const int srow = tid >> 2;      // 0..63
    const int cset = tid & 3;       // 0..3

    for (int kt = 0; kt < KT; ++kt) {
        const int ktb = kbase + kt * KB;
        const float invk0 = kinv[ktb + sr];
        const float invk1 = kinv[ktb + sr + 32];
        float acc[4][4] = {};

        for (int dc = 0; dc < DIM / DC; ++dc) {
            const int d0 = dc * DC;
            // stage A (64 x DC) and B (64 x DC), transposed, normalized
            {
                float4 va = *(const float4*)(Q + (size_t)(qbase + sr) * DIM + d0 + sd);
                As[sd + 0][sr] = va.x * invq0;
                As[sd + 1][sr] = va.y * invq0;
                As[sd + 2][sr] = va.z * invq0;
                As[sd + 3][sr] = va.w * invq0;
                float4 va2 = *(const float4*)(Q + (size_t)(qbase + sr + 32) * DIM + d0 + sd);
                As[sd + 0][sr + 32] = va2.x * invq1;
                As[sd + 1][sr + 32] = va2.y * invq1;
                As[sd + 2][sr + 32] = va2.z * invq1;
                As[sd + 3][sr + 32] = va2.w * invq1;
                float4 vb = *(const float4*)(Kb + (size_t)(ktb + sr) * DIM + d0 + sd);
                Bs[sd + 0][sr] = vb.x * invk0;
                Bs[sd + 1][sr] = vb.y * invk0;
                Bs[sd + 2][sr] = vb.z * invk0;
                Bs[sd + 3][sr] = vb.w * invk0;
                float4 vb2 = *(const float4*)(Kb + (size_t)(ktb + sr + 32) * DIM + d0 + sd);
                Bs[sd + 0][sr + 32] = vb2.x * invk1;
                Bs[sd + 1][sr + 32] = vb2.y * invk1;
                Bs[sd + 2][sr + 32] = vb2.z * invk1;
                Bs[sd + 3][sr + 32] = vb2.w * invk1;
            }
            __syncthreads();
#pragma unroll
            for (int d = 0; d < DC; ++d) {
                float4 a = *(const float4*)(&As[d][rg * 4]);
                float4 b = *(const float4*)(&Bs[d][cg * 4]);
                acc[0][0] = fmaf(a.x, b.x, acc[0][0]);
                acc[0][1] = fmaf(a.x, b.y, acc[0][1]);
                acc[0][2] = fmaf(a.x, b.z, acc[0][2]);
                acc[0][3] = fmaf(a.x, b.w, acc[0][3]);
                acc[1][0] = fmaf(a.y, b.x, acc[1][0]);
                acc[1][1] = fmaf(a.y, b.y, acc[1][1]);
                acc[1][2] = fmaf(a.y, b.z, acc[1][2]);
                acc[1][3] = fmaf(a.y, b.w, acc[1][3]);
                acc[2][0] = fmaf(a.z, b.x, acc[2][0]);
                acc[2][1] = fmaf(a.z, b.y, acc[2][1]);
                acc[2][2] = fmaf(a.z, b.z, acc[2][2]);
                acc[2][3] = fmaf(a.z, b.w, acc[2][3]);
                acc[3][0] = fmaf(a.w, b.x, acc[3][0]);
                acc[3][1] = fmaf(a.w, b.y, acc[3][1]);
                acc[3][2] = fmaf(a.w, b.z, acc[3][2]);
                acc[3][3] = fmaf(a.w, b.w, acc[3][3]);
            }
            __syncthreads();
        }

        // stage sims tile to LDS (aliases As/Bs — already synced above)
#pragma unroll
        for (int i = 0; i < 4; ++i)
#pragma unroll
            for (int j = 0; j < 4; ++j)
                Sims[rg * 4 + i][cg * 4 + j] = acc[i][j];
        __syncthreads();

        // scan 16 candidates (ascending index) into running top-6
#pragma unroll
        for (int s = 0; s < 16; ++s) {
            int c = cset * 16 + s;
            float v = Sims[srow][c];
            insert6(v, ktb + c, tv, ti);
        }
        __syncthreads();   // before next tile's staging overwrites Sims
    }

    // write per-thread partial top-6
    size_t off = (((size_t)(qbase + srow) * 16) + blockIdx.y * 4 + cset) * TOPK;
#pragma unroll
    for (int i = 0; i < TOPK; ++i)
        partials[off + i] = make_float2(tv[i], __int_as_float(ti[i]));
}

// --- 3) merge 16 partial lists per row, count id matches on ranks 1..5 ------
__global__ __launch_bounds__(256) void merge_kernel(
        const float2* __restrict__ partials,
        const int* __restrict__ query_ids, const int* __restrict__ key_ids,
        int* __restrict__ counter) {
    int row = blockIdx.x * blockDim.x + threadIdx.x;   // 0..NROWS-1
    float tv[TOPK]; int ti[TOPK];
#pragma unroll
    for (int i = 0; i < TOPK; ++i) { tv[i] = -INFINITY; ti[i] = 0x7fffffff; }
    const float2* p = partials + (size_t)row * 16 * TOPK;
    for (int l = 0; l < 16 * TOPK; ++l) {
        float2 e = p[l];
        insert6(e.x, __float_as_int(e.y), tv, ti);
    }
    int qid = query_ids[row];
    int cnt = 0;
#pragma unroll
    for (int r = 1; r < TOPK; ++r)               // drop rank 0, keep ranks 1..5
        cnt += (key_ids[ti[r]] == qid) ? 1 : 0;

    for (int o = 32; o; o >>= 1) cnt += __shfl_down(cnt, o, 64);
    __shared__ int sc[4];
    int lane = threadIdx.x & 63, wid = threadIdx.x >> 6;
    if (lane == 0) sc[wid] = cnt;
    __syncthreads();
    if (threadIdx.x == 0) atomicAdd(counter, sc[0] + sc[1] + sc[2] + sc[3]);
}

// --- 4) finalize ------------------------------------------------------------
__global__ void finalize_kernel(const int* __restrict__ counter,
                                float* __restrict__ out) {
    out[0] = (float)(*counter) / (float)(NROWS * KSEL);
}

extern "C" void kernel_launch(void* const* d_in, const int* in_sizes, int n_in,
                              void* d_out, int out_size, void* d_ws, size_t ws_size,
                              hipStream_t stream) {
    (void)in_sizes; (void)n_in; (void)out_size; (void)ws_size;
    const int*   query_ids = (const int*)d_in[0];
    const int*   key_ids   = (const int*)d_in[1];
    const float* q         = (const float*)d_in[2];
    const float* kb        = (const float*)d_in[3];
    // d_in[4] = k (fixed at 5 for this problem)

    char*   ws       = (char*)d_ws;
    int*    counter  = (int*)ws;
    float*  qinv     = (float*)(ws + 256);
    float*  kinv     = (float*)(ws + 256 + 4 * NROWS);
    float2* partials = (float2*)(ws + 256 + 8 * NROWS);

    hipMemsetAsync(counter, 0, sizeof(int), stream);
    norm_kernel<<<2 * NROWS, 256, 0, stream>>>(q, kb, qinv, kinv);
    simtopk_kernel<<<dim3(NROWS / QB, NSLICE), 256, 0, stream>>>(q, kb, qinv, kinv, partials);
    merge_kernel<<<NROWS / 256, 256, 0, stream>>>(partials, query_ids, key_ids, counter);
    finalize_kernel<<<1, 1, 0, stream>>>(counter, (float*)d_out);
}

// Round 2
// 879.250 us; speedup vs baseline: 2.6886x; 2.6886x over previous
//
#include <hip/hip_runtime.h>
#include <math.h>

#define NROWS 8192
#define DIM   1024
#define KSEL  5
#define TOPK  6
#define QB    128            // query rows per block
#define KBT   128            // key cols per tile
#define NSLICE 8
#define KPS   (NROWS / NSLICE)   // keys per slice = 1024
#define NKT   (KPS / KBT)        // key tiles per slice = 8
#define SST   129                // Sims LDS row stride (floats): (r+s)%32 -> 2-way free

typedef __attribute__((ext_vector_type(8))) short bf16x8;
typedef __attribute__((ext_vector_type(4))) float f32x4;

// ---------------------------------------------------------------------------
// ws layout:
//   [0]          : int match counter
//   [256]        : Qh bf16[8192][1024]   (16 MB)
//   [+16M]       : Ql                    (16 MB)
//   [+32M]       : Kh                    (16 MB)
//   [+48M]       : Kl                    (16 MB)
//   [+64M]       : partials float2[8192][16][TOPK]  (~6.3 MB)
// ---------------------------------------------------------------------------

__device__ __forceinline__ unsigned short f2bf(float x) {
    unsigned u = __float_as_uint(x);
    unsigned r = (u + 0x7fffu + ((u >> 16) & 1u)) >> 16;   // RNE
    return (unsigned short)r;
}
__device__ __forceinline__ float bf2f(unsigned short h) {
    return __uint_as_float(((unsigned)h) << 16);
}

__device__ __forceinline__ bool better(float v, int id, float v2, int id2) {
    return (v > v2) || (v == v2 && id < id2);
}
__device__ __forceinline__ void insert6(float v, int id, float* tv, int* ti) {
    if (!better(v, id, tv[TOPK - 1], ti[TOPK - 1])) return;
    int j = TOPK - 1;
    while (j > 0 && better(v, id, tv[j - 1], ti[j - 1])) {
        tv[j] = tv[j - 1]; ti[j] = ti[j - 1]; --j;
    }
    tv[j] = v; ti[j] = id;
}

__device__ __forceinline__ void async16(const unsigned short* g, unsigned short* l) {
    __builtin_amdgcn_global_load_lds(
        (const __attribute__((address_space(1))) void*)g,
        (__attribute__((address_space(3))) void*)l, 16, 0, 0);
}

// --- 1) normalize + split into hi/lo bf16 -----------------------------------
__global__ __launch_bounds__(256) void prep_kernel(
        const float* __restrict__ q, const float* __restrict__ kb,
        unsigned short* __restrict__ Qh, unsigned short* __restrict__ Ql,
        unsigned short* __restrict__ Kh, unsigned short* __restrict__ Kl) {
    const int b = blockIdx.x;
    const bool isQ = (b < NROWS);
    const int r = isQ ? b : b - NROWS;
    const float* src = (isQ ? q : kb) + (size_t)r * DIM;
    unsigned short* Dh = (isQ ? Qh : Kh) + (size_t)r * DIM;
    unsigned short* Dl = (isQ ? Ql : Kl) + (size_t)r * DIM;

    float4 v = *(const float4*)(src + threadIdx.x * 4);
    float s = v.x * v.x + v.y * v.y + v.z * v.z + v.w * v.w;
    for (int o = 32; o; o >>= 1) s += __shfl_down(s, o, 64);
    __shared__ float wsum[4];
    __shared__ float inv_s;
    int lane = threadIdx.x & 63, wid = threadIdx.x >> 6;
    if (lane == 0) wsum[wid] = s;
    __syncthreads();
    if (threadIdx.x == 0)
        inv_s = 1.0f / fmaxf(sqrtf(wsum[0] + wsum[1] + wsum[2] + wsum[3]), 1e-12f);
    __syncthreads();
    const float inv = inv_s;

    float xs[4] = {v.x * inv, v.y * inv, v.z * inv, v.w * inv};
    unsigned short h[4], lo[4];
#pragma unroll
    for (int i = 0; i < 4; ++i) {
        h[i]  = f2bf(xs[i]);
        lo[i] = f2bf(xs[i] - bf2f(h[i]));
    }
    *(ushort4*)(Dh + threadIdx.x * 4) = make_ushort4(h[0], h[1], h[2], h[3]);
    *(ushort4*)(Dl + threadIdx.x * 4) = make_ushort4(lo[0], lo[1], lo[2], lo[3]);
}

// --- 2) MFMA GEMM (hi*hi + hi*lo + lo*hi) + fused per-row top-6 -------------
__global__ __launch_bounds__(256) void gemm_topk_kernel(
        const unsigned short* __restrict__ Qh, const unsigned short* __restrict__ Ql,
        const unsigned short* __restrict__ Kh, const unsigned short* __restrict__ Kl,
        float2* __restrict__ partials) {
    __shared__ unsigned short As[QB * 32];    // [row][k] bf16, 8 KB
    __shared__ unsigned short Bs[KBT * 32];   // [key][k] bf16, 8 KB
    __shared__ float Sims[64 * SST];          // 32.25 KB, reused in 2 row-phases

    const int tid = threadIdx.x;
    const int w = tid >> 6, l = tid & 63;
    const int l15 = l & 15, l4 = l >> 4;
    const int qbase = blockIdx.x * QB;
    const int sbase = blockIdx.y * KPS;
    const int mbase = (w & 1) * 64, nbase = (w >> 1) * 64;

    const int srow  = tid >> 2;          // staging row 0..63 (second pass +64)
    const int skoff = (tid & 3) * 8;     // k offset in bf16 elems (16 B chunks)

    const unsigned short* Aseg[3] = {Qh, Qh, Ql};
    const unsigned short* Bseg[3] = {Kh, Kl, Kh};

    float tv[TOPK]; int ti[TOPK];
#pragma unroll
    for (int i = 0; i < TOPK; ++i) { tv[i] = -INFINITY; ti[i] = 0x7fffffff; }
    const int trow  = tid >> 1;          // persistent top-k row 0..127
    const int thalf = tid & 1;           // col half (64 cols)

    const int fa_off = (mbase + l15) * 32 + l4 * 8;   // + mt*512
    const int fb_off = (nbase + l15) * 32 + l4 * 8;   // + nt*512

    const size_t abase = (size_t)(qbase + srow) * DIM + skoff;

    for (int kt = 0; kt < NKT; ++kt) {
        f32x4 acc[4][4];
#pragma unroll
        for (int mt = 0; mt < 4; ++mt)
#pragma unroll
            for (int nt = 0; nt < 4; ++nt) acc[mt][nt] = (f32x4){0.f, 0.f, 0.f, 0.f};

        const size_t bbase = (size_t)(sbase + kt * KBT + srow) * DIM + skoff;

#pragma unroll 1
        for (int seg = 0; seg < 3; ++seg) {
            const unsigned short* Ag = Aseg[seg];
            const unsigned short* Bg = Bseg[seg];
#pragma unroll 1
            for (int k0 = 0; k0 < DIM; k0 += 32) {
                async16(Ag + abase + k0,                        As + tid * 8);
                async16(Ag + abase + (size_t)64 * DIM + k0,     As + 2048 + tid * 8);
                async16(Bg + bbase + k0,                        Bs + tid * 8);
                async16(Bg + bbase + (size_t)64 * DIM + k0,     Bs + 2048 + tid * 8);
                __syncthreads();   // drains vmcnt (global_load_lds) + aligns
                bf16x8 af[4], bf[4];
#pragma unroll
                for (int mt = 0; mt < 4; ++mt)
                    af[mt] = *(const bf16x8*)(As + fa_off + mt * 512);
#pragma unroll
                for (int nt = 0; nt < 4; ++nt)
                    bf[nt] = *(const bf16x8*)(Bs + fb_off + nt * 512);
#pragma unroll
                for (int mt = 0; mt < 4; ++mt)
#pragma unroll
                    for (int nt = 0; nt < 4; ++nt)
                        acc[mt][nt] = __builtin_amdgcn_mfma_f32_16x16x32_bf16(
                            af[mt], bf[nt], acc[mt][nt], 0, 0, 0);
                __syncthreads();
            }
        }

        // ---- fused top-k over this 128x128 sims tile, two 64-row phases ----
        const int idb = sbase + kt * KBT + thalf * 64;

        // phase 0: rows 0..63 (waves 0,2 hold them: mbase==0)
        if ((w & 1) == 0) {
#pragma unroll
            for (int mt = 0; mt < 4; ++mt) {
                const int r0 = mt * 16 + l4 * 4;
#pragma unroll
                for (int nt = 0; nt < 4; ++nt) {
                    const int c = nbase + nt * 16 + l15;
                    Sims[(r0 + 0) * SST + c] = acc[mt][nt].x;
                    Sims[(r0 + 1) * SST + c] = acc[mt][nt].y;
                    Sims[(r0 + 2) * SST + c] = acc[mt][nt].z;
                    Sims[(r0 + 3) * SST + c] = acc[mt][nt].w;
                }
            }
        }
        __syncthreads();
        if (tid < 128) {
            const float* sp = Sims + trow * SST + thalf * 64;
#pragma unroll 8
            for (int s = 0; s < 64; ++s) insert6(sp[s], idb + s, tv, ti);
        }
        __syncthreads();

        // phase 1: rows 64..127 (waves 1,3: mbase==64), stored at local row
        if ((w & 1) == 1) {
#pragma unroll
            for (int mt = 0; mt < 4; ++mt) {
                const int r0 = mt * 16 + l4 * 4;
#pragma unroll
                for (int nt = 0; nt < 4; ++nt) {
                    const int c = nbase + nt * 16 + l15;
                    Sims[(r0 + 0) * SST + c] = acc[mt][nt].x;
                    Sims[(r0 + 1) * SST + c] = acc[mt][nt].y;
                    Sims[(r0 + 2) * SST + c] = acc[mt][nt].z;
                    Sims[(r0 + 3) * SST + c] = acc[mt][nt].w;
                }
            }
        }
        __syncthreads();
        if (tid >= 128) {
            const float* sp = Sims + (trow - 64) * SST + thalf * 64;
#pragma unroll 8
            for (int s = 0; s < 64; ++s) insert6(sp[s], idb + s, tv, ti);
        }
        __syncthreads();
    }

    size_t off = (((size_t)(qbase + trow) * 16) + blockIdx.y * 2 + thalf) * TOPK;
#pragma unroll
    for (int i = 0; i < TOPK; ++i)
        partials[off + i] = make_float2(tv[i], __int_as_float(ti[i]));
}

// --- 3) merge 16 partial lists per row, count matches on ranks 1..5 ---------
__global__ __launch_bounds__(256) void merge_kernel(
        const float2* __restrict__ partials,
        const int* __restrict__ query_ids, const int* __restrict__ key_ids,
        int* __restrict__ counter) {
    int row = blockIdx.x * blockDim.x + threadIdx.x;
    float tv[TOPK]; int ti[TOPK];
#pragma unroll
    for (int i = 0; i < TOPK; ++i) { tv[i] = -INFINITY; ti[i] = 0x7fffffff; }
    const float2* p = partials + (size_t)row * 16 * TOPK;
    for (int l = 0; l < 16 * TOPK; ++l) {
        float2 e = p[l];
        insert6(e.x, __float_as_int(e.y), tv, ti);
    }
    int qid = query_ids[row];
    int cnt = 0;
#pragma unroll
    for (int r = 1; r < TOPK; ++r)
        cnt += (key_ids[ti[r]] == qid) ? 1 : 0;

    for (int o = 32; o; o >>= 1) cnt += __shfl_down(cnt, o, 64);
    __shared__ int sc[4];
    int lane = threadIdx.x & 63, wid = threadIdx.x >> 6;
    if (lane == 0) sc[wid] = cnt;
    __syncthreads();
    if (threadIdx.x == 0) atomicAdd(counter, sc[0] + sc[1] + sc[2] + sc[3]);
}

// --- 4) finalize ------------------------------------------------------------
__global__ void finalize_kernel(const int* __restrict__ counter,
                                float* __restrict__ out) {
    out[0] = (float)(*counter) / (float)(NROWS * KSEL);
}

extern "C" void kernel_launch(void* const* d_in, const int* in_sizes, int n_in,
                              void* d_out, int out_size, void* d_ws, size_t ws_size,
                              hipStream_t stream) {
    (void)in_sizes; (void)n_in; (void)out_size; (void)ws_size;
    const int*   query_ids = (const int*)d_in[0];
    const int*   key_ids   = (const int*)d_in[1];
    const float* q         = (const float*)d_in[2];
    const float* kb        = (const float*)d_in[3];

    char* ws = (char*)d_ws;
    const size_t MB16 = (size_t)NROWS * DIM * sizeof(unsigned short);  // 16 MB
    int*            counter  = (int*)ws;
    unsigned short* Qh       = (unsigned short*)(ws + 256);
    unsigned short* Ql       = (unsigned short*)(ws + 256 + MB16);
    unsigned short* Kh       = (unsigned short*)(ws + 256 + 2 * MB16);
    unsigned short* Kl       = (unsigned short*)(ws + 256 + 3 * MB16);
    float2*         partials = (float2*)(ws + 256 + 4 * MB16);

    hipMemsetAsync(counter, 0, sizeof(int), stream);
    prep_kernel<<<2 * NROWS, 256, 0, stream>>>(q, kb, Qh, Ql, Kh, Kl);
    gemm_topk_kernel<<<dim3(NROWS / QB, NSLICE), 256, 0, stream>>>(Qh, Ql, Kh, Kl, partials);
    merge_kernel<<<NROWS / 256, 256, 0, stream>>>(partials, query_ids, key_ids, counter);
    finalize_kernel<<<1, 1, 0, stream>>>(counter, (float*)d_out);
}

// Round 3
// 729.493 us; speedup vs baseline: 3.2405x; 1.2053x over previous
//
#include <hip/hip_runtime.h>
#include <math.h>

#define NROWS 8192
#define DIM   1024
#define KSEL  5
#define TOPK  6
#define QB    128            // query rows per block
#define KBT   128            // key cols per tile
#define NSLICE 8
#define KPS   (NROWS / NSLICE)   // keys per slice = 1024
#define NKT   (KPS / KBT)        // key tiles per slice = 8
#define SST   68                 // Sims row stride (floats): 16B aligned, 2-way banks

typedef __attribute__((ext_vector_type(8))) short bf16x8;
typedef __attribute__((ext_vector_type(4))) float f32x4;

// ---------------------------------------------------------------------------
// ws layout:
//   [0]          : int match counter
//   [256]        : Qh bf16[8192][1024]   (16 MB)
//   [+16M]       : Ql                    (16 MB)
//   [+32M]       : Kh                    (16 MB)
//   [+48M]       : Kl                    (16 MB)
//   [+64M]       : partials float2[8192][16][TOPK]  (~6.3 MB)
// ---------------------------------------------------------------------------

__device__ __forceinline__ unsigned short f2bf(float x) {
    unsigned u = __float_as_uint(x);
    unsigned r = (u + 0x7fffu + ((u >> 16) & 1u)) >> 16;   // RNE
    return (unsigned short)r;
}
__device__ __forceinline__ float bf2f(unsigned short h) {
    return __uint_as_float(((unsigned)h) << 16);
}

// full tie-break compare (merge kernel only — arbitrary id order there)
__device__ __forceinline__ bool better(float v, int id, float v2, int id2) {
    return (v > v2) || (v == v2 && id < id2);
}
__device__ __forceinline__ void insert6(float v, int id, float* tv, int* ti) {
    if (!better(v, id, tv[TOPK - 1], ti[TOPK - 1])) return;
    int j = TOPK - 1;
    while (j > 0 && better(v, id, tv[j - 1], ti[j - 1])) {
        tv[j] = tv[j - 1]; ti[j] = ti[j - 1]; --j;
    }
    tv[j] = v; ti[j] = id;
}

// strict insert: candidate ids are strictly ascending within a thread's
// stream, so an equal value must rank below every existing entry — strict
// '>' implements the jax lower-index tie-break exactly.
__device__ __forceinline__ void ins(float v, int id, float* tv, int* ti) {
    if (v <= tv[TOPK - 1]) return;
    int j = TOPK - 1;
    while (j > 0 && v > tv[j - 1]) {
        tv[j] = tv[j - 1]; ti[j] = ti[j - 1]; --j;
    }
    tv[j] = v; ti[j] = id;
}

__device__ __forceinline__ void async16(const unsigned short* g, unsigned short* l) {
    __builtin_amdgcn_global_load_lds(
        (const __attribute__((address_space(1))) void*)g,
        (__attribute__((address_space(3))) void*)l, 16, 0, 0);
}

// --- 1) normalize + split into hi/lo bf16 -----------------------------------
__global__ __launch_bounds__(256) void prep_kernel(
        const float* __restrict__ q, const float* __restrict__ kb,
        unsigned short* __restrict__ Qh, unsigned short* __restrict__ Ql,
        unsigned short* __restrict__ Kh, unsigned short* __restrict__ Kl) {
    const int b = blockIdx.x;
    const bool isQ = (b < NROWS);
    const int r = isQ ? b : b - NROWS;
    const float* src = (isQ ? q : kb) + (size_t)r * DIM;
    unsigned short* Dh = (isQ ? Qh : Kh) + (size_t)r * DIM;
    unsigned short* Dl = (isQ ? Ql : Kl) + (size_t)r * DIM;

    float4 v = *(const float4*)(src + threadIdx.x * 4);
    float s = v.x * v.x + v.y * v.y + v.z * v.z + v.w * v.w;
    for (int o = 32; o; o >>= 1) s += __shfl_down(s, o, 64);
    __shared__ float wsum[4];
    __shared__ float inv_s;
    int lane = threadIdx.x & 63, wid = threadIdx.x >> 6;
    if (lane == 0) wsum[wid] = s;
    __syncthreads();
    if (threadIdx.x == 0)
        inv_s = 1.0f / fmaxf(sqrtf(wsum[0] + wsum[1] + wsum[2] + wsum[3]), 1e-12f);
    __syncthreads();
    const float inv = inv_s;

    float xs[4] = {v.x * inv, v.y * inv, v.z * inv, v.w * inv};
    unsigned short h[4], lo[4];
#pragma unroll
    for (int i = 0; i < 4; ++i) {
        h[i]  = f2bf(xs[i]);
        lo[i] = f2bf(xs[i] - bf2f(h[i]));
    }
    *(ushort4*)(Dh + threadIdx.x * 4) = make_ushort4(h[0], h[1], h[2], h[3]);
    *(ushort4*)(Dl + threadIdx.x * 4) = make_ushort4(lo[0], lo[1], lo[2], lo[3]);
}

// --- 2) MFMA GEMM (hi*hi + hi*lo + lo*hi) + fused per-row top-6 -------------
__global__ __launch_bounds__(256) void gemm_topk_kernel(
        const unsigned short* __restrict__ Qh, const unsigned short* __restrict__ Ql,
        const unsigned short* __restrict__ Kh, const unsigned short* __restrict__ Kl,
        float2* __restrict__ partials) {
    __shared__ unsigned short As[QB * 32];    // 8 KB
    __shared__ unsigned short Bs[KBT * 32];   // 8 KB
    __shared__ float Sims[128 * SST];         // 34 KB (separate; no alias)

    const int tid = threadIdx.x;
    const int w = tid >> 6, l = tid & 63;
    const int l15 = l & 15, l4 = l >> 4;
    const int qbase = blockIdx.x * QB;
    const int sbase = blockIdx.y * KPS;
    const int mbase = (w & 1) * 64, nbase = (w >> 1) * 64;

    const int srow  = tid >> 2;          // staging row 0..63 (second half +64)
    const int skoff = (tid & 3) * 8;     // k offset in bf16 elems (16 B chunks)

    const unsigned short* Aseg[3] = {Qh, Qh, Ql};
    const unsigned short* Bseg[3] = {Kh, Kl, Kh};

    float tv[TOPK]; int ti[TOPK];
#pragma unroll
    for (int i = 0; i < TOPK; ++i) { tv[i] = -INFINITY; ti[i] = 0x7fffffff; }
    const int trow = tid >> 1;           // persistent top-k row 0..127
    const int tq   = tid & 1;            // 32-col quarter selector

    const int fa_off = (mbase + l15) * 32 + l4 * 8;   // + mt*512
    const int fb_off = (nbase + l15) * 32 + l4 * 8;   // + nt*512

    const size_t abase = (size_t)(qbase + srow) * DIM + skoff;

    for (int kt = 0; kt < NKT; ++kt) {
        f32x4 acc[4][4];
#pragma unroll
        for (int mt = 0; mt < 4; ++mt)
#pragma unroll
            for (int nt = 0; nt < 4; ++nt) acc[mt][nt] = (f32x4){0.f, 0.f, 0.f, 0.f};

        const size_t bbase = (size_t)(sbase + kt * KBT + srow) * DIM + skoff;

#pragma unroll 1
        for (int seg = 0; seg < 3; ++seg) {
            const unsigned short* Ag = Aseg[seg];
            const unsigned short* Bg = Bseg[seg];
#pragma unroll 1
            for (int k0 = 0; k0 < DIM; k0 += 32) {
                async16(Ag + abase + k0,                        As + tid * 8);
                async16(Ag + abase + (size_t)64 * DIM + k0,     As + 2048 + tid * 8);
                async16(Bg + bbase + k0,                        Bs + tid * 8);
                async16(Bg + bbase + (size_t)64 * DIM + k0,     Bs + 2048 + tid * 8);
                __syncthreads();   // drains vmcnt (global_load_lds)
                bf16x8 af[4], bf[4];
#pragma unroll
                for (int mt = 0; mt < 4; ++mt)
                    af[mt] = *(const bf16x8*)(As + fa_off + mt * 512);
#pragma unroll
                for (int nt = 0; nt < 4; ++nt)
                    bf[nt] = *(const bf16x8*)(Bs + fb_off + nt * 512);
#pragma unroll
                for (int mt = 0; mt < 4; ++mt)
#pragma unroll
                    for (int nt = 0; nt < 4; ++nt)
                        acc[mt][nt] = __builtin_amdgcn_mfma_f32_16x16x32_bf16(
                            af[mt], bf[nt], acc[mt][nt], 0, 0, 0);
                __syncthreads();
            }
        }

        // ---- fused top-k: two col-half phases, all 256 threads scan --------
        const int tile0 = sbase + kt * KBT;

        // phase A: waves 0,1 (nbase==0) hold cols 0..63 for all 128 rows
        if (nbase == 0) {
#pragma unroll
            for (int mt = 0; mt < 4; ++mt) {
                const int r0 = mbase + mt * 16 + l4 * 4;
#pragma unroll
                for (int nt = 0; nt < 4; ++nt) {
                    const int c = nt * 16 + l15;        // local col 0..63
                    Sims[(r0 + 0) * SST + c] = acc[mt][nt].x;
                    Sims[(r0 + 1) * SST + c] = acc[mt][nt].y;
                    Sims[(r0 + 2) * SST + c] = acc[mt][nt].z;
                    Sims[(r0 + 3) * SST + c] = acc[mt][nt].w;
                }
            }
        }
        __syncthreads();
        {
            const float* sp = Sims + trow * SST + tq * 32;
            const int idc0 = tile0 + tq * 32;
#pragma unroll
            for (int j = 0; j < 8; ++j) {
                float4 v = *(const float4*)(sp + 4 * j);
                float m = fmaxf(fmaxf(v.x, v.y), fmaxf(v.z, v.w));
                if (m > tv[TOPK - 1]) {
                    const int idc = idc0 + 4 * j;
                    ins(v.x, idc + 0, tv, ti);
                    ins(v.y, idc + 1, tv, ti);
                    ins(v.z, idc + 2, tv, ti);
                    ins(v.w, idc + 3, tv, ti);
                }
            }
        }
        __syncthreads();

        // phase B: waves 2,3 (nbase==64) hold cols 64..127
        if (nbase == 64) {
#pragma unroll
            for (int mt = 0; mt < 4; ++mt) {
                const int r0 = mbase + mt * 16 + l4 * 4;
#pragma unroll
                for (int nt = 0; nt < 4; ++nt) {
                    const int c = nt * 16 + l15;        // local col 0..63
                    Sims[(r0 + 0) * SST + c] = acc[mt][nt].x;
                    Sims[(r0 + 1) * SST + c] = acc[mt][nt].y;
                    Sims[(r0 + 2) * SST + c] = acc[mt][nt].z;
                    Sims[(r0 + 3) * SST + c] = acc[mt][nt].w;
                }
            }
        }
        __syncthreads();
        {
            const float* sp = Sims + trow * SST + tq * 32;
            const int idc0 = tile0 + 64 + tq * 32;
#pragma unroll
            for (int j = 0; j < 8; ++j) {
                float4 v = *(const float4*)(sp + 4 * j);
                float m = fmaxf(fmaxf(v.x, v.y), fmaxf(v.z, v.w));
                if (m > tv[TOPK - 1]) {
                    const int idc = idc0 + 4 * j;
                    ins(v.x, idc + 0, tv, ti);
                    ins(v.y, idc + 1, tv, ti);
                    ins(v.z, idc + 2, tv, ti);
                    ins(v.w, idc + 3, tv, ti);
                }
            }
        }
        // no barrier needed: next kt's staging barrier precedes any Sims reuse
    }

    size_t off = (((size_t)(qbase + trow) * 16) + blockIdx.y * 2 + tq) * TOPK;
#pragma unroll
    for (int i = 0; i < TOPK; ++i)
        partials[off + i] = make_float2(tv[i], __int_as_float(ti[i]));
}

// --- 3) merge 16 partial lists per row, count matches on ranks 1..5 ---------
__global__ __launch_bounds__(256) void merge_kernel(
        const float2* __restrict__ partials,
        const int* __restrict__ query_ids, const int* __restrict__ key_ids,
        int* __restrict__ counter) {
    int row = blockIdx.x * blockDim.x + threadIdx.x;
    float tv[TOPK]; int ti[TOPK];
#pragma unroll
    for (int i = 0; i < TOPK; ++i) { tv[i] = -INFINITY; ti[i] = 0x7fffffff; }
    const float2* p = partials + (size_t)row * 16 * TOPK;
    for (int l = 0; l < 16 * TOPK; ++l) {
        float2 e = p[l];
        insert6(e.x, __float_as_int(e.y), tv, ti);
    }
    int qid = query_ids[row];
    int cnt = 0;
#pragma unroll
    for (int r = 1; r < TOPK; ++r)
        cnt += (key_ids[ti[r]] == qid) ? 1 : 0;

    for (int o = 32; o; o >>= 1) cnt += __shfl_down(cnt, o, 64);
    __shared__ int sc[4];
    int lane = threadIdx.x & 63, wid = threadIdx.x >> 6;
    if (lane == 0) sc[wid] = cnt;
    __syncthreads();
    if (threadIdx.x == 0) atomicAdd(counter, sc[0] + sc[1] + sc[2] + sc[3]);
}

// --- 4) finalize ------------------------------------------------------------
__global__ void finalize_kernel(const int* __restrict__ counter,
                                float* __restrict__ out) {
    out[0] = (float)(*counter) / (float)(NROWS * KSEL);
}

extern "C" void kernel_launch(void* const* d_in, const int* in_sizes, int n_in,
                              void* d_out, int out_size, void* d_ws, size_t ws_size,
                              hipStream_t stream) {
    (void)in_sizes; (void)n_in; (void)out_size; (void)ws_size;
    const int*   query_ids = (const int*)d_in[0];
    const int*   key_ids   = (const int*)d_in[1];
    const float* q         = (const float*)d_in[2];
    const float* kb        = (const float*)d_in[3];

    char* ws = (char*)d_ws;
    const size_t MB16 = (size_t)NROWS * DIM * sizeof(unsigned short);  // 16 MB
    int*            counter  = (int*)ws;
    unsigned short* Qh       = (unsigned short*)(ws + 256);
    unsigned short* Ql       = (unsigned short*)(ws + 256 + MB16);
    unsigned short* Kh       = (unsigned short*)(ws + 256 + 2 * MB16);
    unsigned short* Kl       = (unsigned short*)(ws + 256 + 3 * MB16);
    float2*         partials = (float2*)(ws + 256 + 4 * MB16);

    hipMemsetAsync(counter, 0, sizeof(int), stream);
    prep_kernel<<<2 * NROWS, 256, 0, stream>>>(q, kb, Qh, Ql, Kh, Kl);
    gemm_topk_kernel<<<dim3(NROWS / QB, NSLICE), 256, 0, stream>>>(Qh, Ql, Kh, Kl, partials);
    merge_kernel<<<NROWS / 256, 256, 0, stream>>>(partials, query_ids, key_ids, counter);
    finalize_kernel<<<1, 1, 0, stream>>>(counter, (float*)d_out);
}

// Round 4
// 661.761 us; speedup vs baseline: 3.5722x; 1.1024x over previous
//
#include <hip/hip_runtime.h>
#include <math.h>

#define NROWS 8192
#define DIM   1024
#define DIM2  2048           // merged hi|lo K dimension
#define KSEL  5
#define TOPK  6
#define QB    128            // query rows per block
#define KBT   128            // key cols per tile
#define NSLICE 16
#define KPS   (NROWS / NSLICE)   // keys per slice = 512
#define NKT   (KPS / KBT)        // key tiles per slice = 4
#define SST   68                 // Sims row stride (floats), 16B aligned

typedef __attribute__((ext_vector_type(8))) short bf16x8;
typedef __attribute__((ext_vector_type(4))) float f32x4;

// ---------------------------------------------------------------------------
// ws layout:
//   [0]          : int match counter
//   [256]        : Q2 bf16[8192][2048]  (hi | lo)   32 MB
//   [+32M]       : K2 bf16[8192][2048]  (hi | lo)   32 MB
//   [+64M]       : partials float2[8192][32][TOPK]  (~12.6 MB)
// sims = Q2·K2^T = qh·kh + qh·kl + ql·kh + ql·kl; the lolo term is ~2^-18
// relative — below fp32 accumulation noise, so ONE K=2048 bf16 GEMM suffices.
// ---------------------------------------------------------------------------

__device__ __forceinline__ unsigned short f2bf(float x) {
    unsigned u = __float_as_uint(x);
    unsigned r = (u + 0x7fffu + ((u >> 16) & 1u)) >> 16;   // RNE
    return (unsigned short)r;
}
__device__ __forceinline__ float bf2f(unsigned short h) {
    return __uint_as_float(((unsigned)h) << 16);
}

// full tie-break compare (merge kernel only — arbitrary id order there)
__device__ __forceinline__ bool better(float v, int id, float v2, int id2) {
    return (v > v2) || (v == v2 && id < id2);
}
__device__ __forceinline__ void insert6(float v, int id, float* tv, int* ti) {
    if (!better(v, id, tv[TOPK - 1], ti[TOPK - 1])) return;
    int j = TOPK - 1;
    while (j > 0 && better(v, id, tv[j - 1], ti[j - 1])) {
        tv[j] = tv[j - 1]; ti[j] = ti[j - 1]; --j;
    }
    tv[j] = v; ti[j] = id;
}

// strict insert: candidate ids strictly ascending per thread stream, so
// strict '>' implements the lower-index tie-break exactly.
__device__ __forceinline__ void ins(float v, int id, float* tv, int* ti) {
    if (v <= tv[TOPK - 1]) return;
    int j = TOPK - 1;
    while (j > 0 && v > tv[j - 1]) {
        tv[j] = tv[j - 1]; ti[j] = ti[j - 1]; --j;
    }
    tv[j] = v; ti[j] = id;
}

__device__ __forceinline__ void async16(const unsigned short* g, unsigned short* l) {
    __builtin_amdgcn_global_load_lds(
        (const __attribute__((address_space(1))) void*)g,
        (__attribute__((address_space(3))) void*)l, 16, 0, 0);
}

// --- 1) normalize + split into hi/lo bf16, packed [hi | lo] per row ---------
__global__ __launch_bounds__(256) void prep_kernel(
        const float* __restrict__ q, const float* __restrict__ kb,
        unsigned short* __restrict__ Q2, unsigned short* __restrict__ K2) {
    const int b = blockIdx.x;
    const bool isQ = (b < NROWS);
    const int r = isQ ? b : b - NROWS;
    const float* src = (isQ ? q : kb) + (size_t)r * DIM;
    unsigned short* D = (isQ ? Q2 : K2) + (size_t)r * DIM2;

    float4 v = *(const float4*)(src + threadIdx.x * 4);
    float s = v.x * v.x + v.y * v.y + v.z * v.z + v.w * v.w;
    for (int o = 32; o; o >>= 1) s += __shfl_down(s, o, 64);
    __shared__ float wsum[4];
    __shared__ float inv_s;
    int lane = threadIdx.x & 63, wid = threadIdx.x >> 6;
    if (lane == 0) wsum[wid] = s;
    __syncthreads();
    if (threadIdx.x == 0)
        inv_s = 1.0f / fmaxf(sqrtf(wsum[0] + wsum[1] + wsum[2] + wsum[3]), 1e-12f);
    __syncthreads();
    const float inv = inv_s;

    float xs[4] = {v.x * inv, v.y * inv, v.z * inv, v.w * inv};
    unsigned short h[4], lo[4];
#pragma unroll
    for (int i = 0; i < 4; ++i) {
        h[i]  = f2bf(xs[i]);
        lo[i] = f2bf(xs[i] - bf2f(h[i]));
    }
    *(ushort4*)(D + threadIdx.x * 4)       = make_ushort4(h[0], h[1], h[2], h[3]);
    *(ushort4*)(D + DIM + threadIdx.x * 4) = make_ushort4(lo[0], lo[1], lo[2], lo[3]);
}

// --- 2) single K=2048 MFMA GEMM + fused per-row top-6 -----------------------
__global__ __launch_bounds__(256) void gemm_topk_kernel(
        const unsigned short* __restrict__ Q2, const unsigned short* __restrict__ K2,
        float2* __restrict__ partials) {
    __shared__ unsigned short As[QB * 32];    // 8 KB
    __shared__ unsigned short Bs[KBT * 32];   // 8 KB
    __shared__ float Sims[128 * SST];         // 34 KB

    const int tid = threadIdx.x;
    const int w = tid >> 6, l = tid & 63;
    const int l15 = l & 15, l4 = l >> 4;
    const int qbase = blockIdx.x * QB;
    const int sbase = blockIdx.y * KPS;
    const int mbase = (w & 1) * 64, nbase = (w >> 1) * 64;

    const int srow  = tid >> 2;          // staging row 0..63 (second half +64)
    const int skoff = (tid & 3) * 8;     // k offset in bf16 elems (16 B chunks)

    float tv[TOPK]; int ti[TOPK];
#pragma unroll
    for (int i = 0; i < TOPK; ++i) { tv[i] = -INFINITY; ti[i] = 0x7fffffff; }
    const int trow = tid >> 1;           // persistent top-k row 0..127
    const int tq   = tid & 1;            // 32-col quarter selector

    const int fa_off = (mbase + l15) * 32 + l4 * 8;   // + mt*512
    const int fb_off = (nbase + l15) * 32 + l4 * 8;   // + nt*512

    const size_t abase = (size_t)(qbase + srow) * DIM2 + skoff;

    for (int kt = 0; kt < NKT; ++kt) {
        f32x4 acc[4][4];
#pragma unroll
        for (int mt = 0; mt < 4; ++mt)
#pragma unroll
            for (int nt = 0; nt < 4; ++nt) acc[mt][nt] = (f32x4){0.f, 0.f, 0.f, 0.f};

        const size_t bbase = (size_t)(sbase + kt * KBT + srow) * DIM2 + skoff;

#pragma unroll 1
        for (int k0 = 0; k0 < DIM2; k0 += 32) {
            async16(Q2 + abase + k0,                       As + tid * 8);
            async16(Q2 + abase + (size_t)64 * DIM2 + k0,   As + 2048 + tid * 8);
            async16(K2 + bbase + k0,                       Bs + tid * 8);
            async16(K2 + bbase + (size_t)64 * DIM2 + k0,   Bs + 2048 + tid * 8);
            __syncthreads();   // drains vmcnt (global_load_lds)
            bf16x8 af[4], bf[4];
#pragma unroll
            for (int mt = 0; mt < 4; ++mt)
                af[mt] = *(const bf16x8*)(As + fa_off + mt * 512);
#pragma unroll
            for (int nt = 0; nt < 4; ++nt)
                bf[nt] = *(const bf16x8*)(Bs + fb_off + nt * 512);
#pragma unroll
            for (int mt = 0; mt < 4; ++mt)
#pragma unroll
                for (int nt = 0; nt < 4; ++nt)
                    acc[mt][nt] = __builtin_amdgcn_mfma_f32_16x16x32_bf16(
                        af[mt], bf[nt], acc[mt][nt], 0, 0, 0);
            __syncthreads();
        }

        // ---- fused top-k: two col-half phases, all 256 threads scan --------
        const int tile0 = sbase + kt * KBT;

        // phase A: waves 0,1 (nbase==0) hold cols 0..63 for all 128 rows
        if (nbase == 0) {
#pragma unroll
            for (int mt = 0; mt < 4; ++mt) {
                const int r0 = mbase + mt * 16 + l4 * 4;
#pragma unroll
                for (int nt = 0; nt < 4; ++nt) {
                    const int c = nt * 16 + l15;        // local col 0..63
                    Sims[(r0 + 0) * SST + c] = acc[mt][nt].x;
                    Sims[(r0 + 1) * SST + c] = acc[mt][nt].y;
                    Sims[(r0 + 2) * SST + c] = acc[mt][nt].z;
                    Sims[(r0 + 3) * SST + c] = acc[mt][nt].w;
                }
            }
        }
        __syncthreads();
        {
            const float* sp = Sims + trow * SST + tq * 32;
            const int idc0 = tile0 + tq * 32;
#pragma unroll
            for (int j = 0; j < 8; ++j) {
                float4 v = *(const float4*)(sp + 4 * j);
                float m = fmaxf(fmaxf(v.x, v.y), fmaxf(v.z, v.w));
                if (m > tv[TOPK - 1]) {
                    const int idc = idc0 + 4 * j;
                    ins(v.x, idc + 0, tv, ti);
                    ins(v.y, idc + 1, tv, ti);
                    ins(v.z, idc + 2, tv, ti);
                    ins(v.w, idc + 3, tv, ti);
                }
            }
        }
        __syncthreads();

        // phase B: waves 2,3 (nbase==64) hold cols 64..127
        if (nbase == 64) {
#pragma unroll
            for (int mt = 0; mt < 4; ++mt) {
                const int r0 = mbase + mt * 16 + l4 * 4;
#pragma unroll
                for (int nt = 0; nt < 4; ++nt) {
                    const int c = nt * 16 + l15;        // local col 0..63
                    Sims[(r0 + 0) * SST + c] = acc[mt][nt].x;
                    Sims[(r0 + 1) * SST + c] = acc[mt][nt].y;
                    Sims[(r0 + 2) * SST + c] = acc[mt][nt].z;
                    Sims[(r0 + 3) * SST + c] = acc[mt][nt].w;
                }
            }
        }
        __syncthreads();
        {
            const float* sp = Sims + trow * SST + tq * 32;
            const int idc0 = tile0 + 64 + tq * 32;
#pragma unroll
            for (int j = 0; j < 8; ++j) {
                float4 v = *(const float4*)(sp + 4 * j);
                float m = fmaxf(fmaxf(v.x, v.y), fmaxf(v.z, v.w));
                if (m > tv[TOPK - 1]) {
                    const int idc = idc0 + 4 * j;
                    ins(v.x, idc + 0, tv, ti);
                    ins(v.y, idc + 1, tv, ti);
                    ins(v.z, idc + 2, tv, ti);
                    ins(v.w, idc + 3, tv, ti);
                }
            }
        }
        // no barrier needed: next kt's staging barrier precedes Sims reuse
    }

    size_t off = (((size_t)(qbase + trow) * 2 * NSLICE) + blockIdx.y * 2 + tq) * TOPK;
#pragma unroll
    for (int i = 0; i < TOPK; ++i)
        partials[off + i] = make_float2(tv[i], __int_as_float(ti[i]));
}

// --- 3) merge 32 partial lists per row, count matches on ranks 1..5 ---------
__global__ __launch_bounds__(256) void merge_kernel(
        const float2* __restrict__ partials,
        const int* __restrict__ query_ids, const int* __restrict__ key_ids,
        int* __restrict__ counter) {
    int row = blockIdx.x * blockDim.x + threadIdx.x;
    float tv[TOPK]; int ti[TOPK];
#pragma unroll
    for (int i = 0; i < TOPK; ++i) { tv[i] = -INFINITY; ti[i] = 0x7fffffff; }
    const float2* p = partials + (size_t)row * 2 * NSLICE * TOPK;
    for (int l = 0; l < 2 * NSLICE * TOPK; ++l) {
        float2 e = p[l];
        insert6(e.x, __float_as_int(e.y), tv, ti);
    }
    int qid = query_ids[row];
    int cnt = 0;
#pragma unroll
    for (int r = 1; r < TOPK; ++r)
        cnt += (key_ids[ti[r]] == qid) ? 1 : 0;

    for (int o = 32; o; o >>= 1) cnt += __shfl_down(cnt, o, 64);
    __shared__ int sc[4];
    int lane = threadIdx.x & 63, wid = threadIdx.x >> 6;
    if (lane == 0) sc[wid] = cnt;
    __syncthreads();
    if (threadIdx.x == 0) atomicAdd(counter, sc[0] + sc[1] + sc[2] + sc[3]);
}

// --- 4) finalize ------------------------------------------------------------
__global__ void finalize_kernel(const int* __restrict__ counter,
                                float* __restrict__ out) {
    out[0] = (float)(*counter) / (float)(NROWS * KSEL);
}

extern "C" void kernel_launch(void* const* d_in, const int* in_sizes, int n_in,
                              void* d_out, int out_size, void* d_ws, size_t ws_size,
                              hipStream_t stream) {
    (void)in_sizes; (void)n_in; (void)out_size; (void)ws_size;
    const int*   query_ids = (const int*)d_in[0];
    const int*   key_ids   = (const int*)d_in[1];
    const float* q         = (const float*)d_in[2];
    const float* kb        = (const float*)d_in[3];

    char* ws = (char*)d_ws;
    const size_t MB32 = (size_t)NROWS * DIM2 * sizeof(unsigned short);  // 32 MB
    int*            counter  = (int*)ws;
    unsigned short* Q2       = (unsigned short*)(ws + 256);
    unsigned short* K2       = (unsigned short*)(ws + 256 + MB32);
    float2*         partials = (float2*)(ws + 256 + 2 * MB32);

    hipMemsetAsync(counter, 0, sizeof(int), stream);
    prep_kernel<<<2 * NROWS, 256, 0, stream>>>(q, kb, Q2, K2);
    gemm_topk_kernel<<<dim3(NROWS / QB, NSLICE), 256, 0, stream>>>(Q2, K2, partials);
    merge_kernel<<<NROWS / 256, 256, 0, stream>>>(partials, query_ids, key_ids, counter);
    finalize_kernel<<<1, 1, 0, stream>>>(counter, (float*)d_out);
}